// Round 2
// baseline (94.610 us; speedup 1.0000x reference)
//
#include <hip/hip_runtime.h>
#include <hip/hip_bf16.h>

typedef __bf16 bf16x8 __attribute__((ext_vector_type(8)));
typedef float  f32x4  __attribute__((ext_vector_type(4)));

#define IN_F   4096
#define OUT_F  4096
#define RANK   32
#define BM     16
#define NTHR   1024
#define NW     (NTHR / 64)   // 16 waves

__device__ __forceinline__ bf16x8 cvt8(float4 a, float4 b) {
    bf16x8 r;
    r[0] = (__bf16)a.x; r[1] = (__bf16)a.y; r[2] = (__bf16)a.z; r[3] = (__bf16)a.w;
    r[4] = (__bf16)b.x; r[5] = (__bf16)b.y; r[6] = (__bf16)b.z; r[7] = (__bf16)b.w;
    return r;
}

__global__ __launch_bounds__(NTHR)
void lora_fused(const float* __restrict__ X, const float* __restrict__ U,
                const float* __restrict__ S, const float* __restrict__ V,
                float* __restrict__ Out)
{
    __shared__ float Hp[NW][BM][RANK];     // per-wave K-partial H  (32 KB)
    __shared__ float Hs[BM][RANK + 4];     // reduced H, padded stride 36

    const int tid  = threadIdx.x;
    const int wave = tid >> 6;             // 0..15
    const int lane = tid & 63;
    const int row  = lane & 15;            // MFMA row / col index
    const int kg   = lane >> 4;            // 0..3 k-group

    const int t0 = blockIdx.x * BM;        // first token of this block

    // ---------- Stage 1: H_partial = X_tile @ V^T over this wave's K slice ----------
    // Each wave owns IN_F/NW = 256 features -> 8 MFMA steps of K=32.
    f32x4 acc0 = {0.f, 0.f, 0.f, 0.f};
    f32x4 acc1 = {0.f, 0.f, 0.f, 0.f};

    const float* xptr  = X + (size_t)(t0 + row) * IN_F + wave * (IN_F / NW) + kg * 8;
    const float* v0ptr = V + (size_t)row        * IN_F + wave * (IN_F / NW) + kg * 8;
    const float* v1ptr = V + (size_t)(16 + row) * IN_F + wave * (IN_F / NW) + kg * 8;

    #pragma unroll
    for (int ks = 0; ks < IN_F / NW / 32; ++ks) {   // 8 steps x K=32
        const float4* ap  = reinterpret_cast<const float4*>(xptr  + ks * 32);
        const float4* b0p = reinterpret_cast<const float4*>(v0ptr + ks * 32);
        const float4* b1p = reinterpret_cast<const float4*>(v1ptr + ks * 32);
        float4 a0 = ap[0],  a1 = ap[1];
        float4 c0 = b0p[0], c1 = b0p[1];
        float4 d0 = b1p[0], d1 = b1p[1];
        bf16x8 af  = cvt8(a0, a1);
        bf16x8 bf0 = cvt8(c0, c1);
        bf16x8 bf1 = cvt8(d0, d1);
        acc0 = __builtin_amdgcn_mfma_f32_16x16x32_bf16(af, bf0, acc0, 0, 0, 0);
        acc1 = __builtin_amdgcn_mfma_f32_16x16x32_bf16(af, bf1, acc1, 0, 0, 0);
    }

    // D layout (verified m89): col = lane&15 (rank), row = kg*4+j (token)
    #pragma unroll
    for (int j = 0; j < 4; ++j) {
        Hp[wave][kg * 4 + j][row]      = acc0[j];
        Hp[wave][kg * 4 + j][16 + row] = acc1[j];
    }
    __syncthreads();

    // reduce the NW K-partials, apply S
    if (tid < BM * RANK) {
        int tok = tid >> 5, r = tid & 31;
        float s = 0.f;
        #pragma unroll
        for (int w = 0; w < NW; ++w) s += Hp[w][tok][r];
        Hs[tok][r] = s * S[r];             // SCALING == 1.0, folded out
    }
    __syncthreads();

    // ---------- Stage 2: Out_tile = H @ U^T (K = RANK = 32, one MFMA per 16x16 tile) ----------
    bf16x8 ha;
    #pragma unroll
    for (int j = 0; j < 8; ++j) ha[j] = (__bf16)Hs[row][kg * 8 + j];

    float* obase = Out + (size_t)(t0 + kg * 4) * OUT_F + row;

    #pragma unroll 4
    for (int i = 0; i < OUT_F / 16 / NW; ++i) {      // 16 tiles per wave
        int o0 = (i * NW + wave) * 16;   // waves interleave n-tiles for store adjacency
        const float4* up = reinterpret_cast<const float4*>(
            U + (size_t)(o0 + row) * RANK + kg * 8);
        float4 u0 = up[0], u1 = up[1];
        bf16x8 bu = cvt8(u0, u1);
        f32x4 d = {0.f, 0.f, 0.f, 0.f};
        d = __builtin_amdgcn_mfma_f32_16x16x32_bf16(ha, bu, d, 0, 0, 0);
        #pragma unroll
        for (int j = 0; j < 4; ++j)
            obase[(size_t)j * OUT_F + o0] = d[j];
    }
}

extern "C" void kernel_launch(void* const* d_in, const int* in_sizes, int n_in,
                              void* d_out, int out_size, void* d_ws, size_t ws_size,
                              hipStream_t stream) {
    const float* X = (const float*)d_in[0];
    const float* U = (const float*)d_in[1];
    const float* S = (const float*)d_in[2];
    const float* V = (const float*)d_in[3];
    float* Out = (float*)d_out;

    dim3 grid(8192 / BM);   // 512 blocks x 1024 threads -> 2 blocks/CU, 32 waves/CU
    lora_fused<<<grid, NTHR, 0, stream>>>(X, U, S, V, Out);
}

// Round 4
// 92.810 us; speedup vs baseline: 1.0194x; 1.0194x over previous
//
#include <hip/hip_runtime.h>
#include <hip/hip_bf16.h>

typedef __bf16 bf16x8 __attribute__((ext_vector_type(8)));
typedef float  f32x4  __attribute__((ext_vector_type(4)));

#define IN_F   4096
#define OUT_F  4096
#define RANK   32
#define BM     16

__device__ __forceinline__ bf16x8 cvt8(float4 a, float4 b) {
    bf16x8 r;
    r[0] = (__bf16)a.x; r[1] = (__bf16)a.y; r[2] = (__bf16)a.z; r[3] = (__bf16)a.w;
    r[4] = (__bf16)b.x; r[5] = (__bf16)b.y; r[6] = (__bf16)b.z; r[7] = (__bf16)b.w;
    return r;
}

// ---------------- Kernel 1: H partials = X @ V^T  (K-split across gridDim.y) ----------
// grid (512, KS), block 256 (4 waves). Block (tt, ksb) covers tokens [tt*16, tt*16+16)
// over features [ksb*(IN_F/KS), ...). Waves split that slice by 4.
template <int KS>
__global__ __launch_bounds__(256, 4)
void lora_h(const float* __restrict__ X, const float* __restrict__ S,
            const float* __restrict__ V, float* __restrict__ Hpart)
{
    constexpr int SLICE = IN_F / KS;        // features per block
    constexpr int WSLICE = SLICE / 4;       // features per wave
    constexpr int STEPS = WSLICE / 32;      // MFMA K-steps per wave

    __shared__ float Hp[4][BM][RANK + 1];   // per-wave partials, padded

    const int tid  = threadIdx.x;
    const int wave = tid >> 6;
    const int lane = tid & 63;
    const int row  = lane & 15;
    const int kg   = lane >> 4;

    const int t0 = blockIdx.x * BM;
    const int f0 = blockIdx.y * SLICE + wave * WSLICE + kg * 8;

    f32x4 acc0 = {0.f, 0.f, 0.f, 0.f};
    f32x4 acc1 = {0.f, 0.f, 0.f, 0.f};

    const float* xptr  = X + (size_t)(t0 + row) * IN_F + f0;
    const float* v0ptr = V + (size_t)row        * IN_F + f0;
    const float* v1ptr = V + (size_t)(16 + row) * IN_F + f0;

    #pragma unroll
    for (int ks = 0; ks < STEPS; ++ks) {
        const float4* ap  = reinterpret_cast<const float4*>(xptr  + ks * 32);
        const float4* b0p = reinterpret_cast<const float4*>(v0ptr + ks * 32);
        const float4* b1p = reinterpret_cast<const float4*>(v1ptr + ks * 32);
        float4 a0 = ap[0],  a1 = ap[1];
        float4 c0 = b0p[0], c1 = b0p[1];
        float4 d0 = b1p[0], d1 = b1p[1];
        bf16x8 af  = cvt8(a0, a1);
        bf16x8 bf0 = cvt8(c0, c1);
        bf16x8 bf1 = cvt8(d0, d1);
        acc0 = __builtin_amdgcn_mfma_f32_16x16x32_bf16(af, bf0, acc0, 0, 0, 0);
        acc1 = __builtin_amdgcn_mfma_f32_16x16x32_bf16(af, bf1, acc1, 0, 0, 0);
    }

    // D layout: col(=rank)=lane&15, row(=token)=kg*4+j
    #pragma unroll
    for (int j = 0; j < 4; ++j) {
        Hp[wave][kg * 4 + j][row]      = acc0[j];
        Hp[wave][kg * 4 + j][16 + row] = acc1[j];
    }
    __syncthreads();

    // reduce 4 wave-partials, apply S, write block partial
    float* dst = Hpart + ((size_t)blockIdx.y * 512 + blockIdx.x) * (BM * RANK);
    for (int i = tid; i < BM * RANK; i += 256) {
        int tok = i >> 5, r = i & 31;
        float s = Hp[0][tok][r] + Hp[1][tok][r] + Hp[2][tok][r] + Hp[3][tok][r];
        dst[i] = s * S[r];                  // SCALING == 1.0 folded
    }
}

// ---------------- Kernel 2: Out = H @ U^T ----------------
// grid 2048, block 256 (4 waves). Block b: token-tile tt = b>>2, col-quarter cq = b&3.
__global__ __launch_bounds__(256, 4)
void lora_out(const float* __restrict__ Hpart, const float* __restrict__ U,
              float* __restrict__ Out, int nks)
{
    __shared__ float Hs[BM][RANK + 1];

    const int tid  = threadIdx.x;
    const int wave = tid >> 6;
    const int lane = tid & 63;
    const int row  = lane & 15;
    const int kg   = lane >> 4;

    const int tt = blockIdx.x >> 2;
    const int cq = blockIdx.x & 3;
    const int t0 = tt * BM;

    // reduce K-split partials for this token tile (512 elements, strided over 256 thr)
    for (int i = tid; i < BM * RANK; i += 256) {
        float s = 0.f;
        for (int k = 0; k < nks; ++k)
            s += Hpart[((size_t)k * 512 + tt) * (BM * RANK) + i];
        Hs[i >> 5][i & 31] = s;
    }
    __syncthreads();

    // A fragment: token = row, k(rank) = kg*8+j
    bf16x8 ha;
    #pragma unroll
    for (int j = 0; j < 8; ++j) ha[j] = (__bf16)Hs[row][kg * 8 + j];

    float* obase = Out + (size_t)(t0 + kg * 4) * OUT_F + row;

    #pragma unroll 4
    for (int i = 0; i < 16; ++i) {          // 16 tiles per wave -> 1024 out-cols per block
        int o0 = cq * 1024 + (i * 4 + wave) * 16;
        const float4* up = reinterpret_cast<const float4*>(
            U + (size_t)(o0 + row) * RANK + kg * 8);
        float4 u0 = up[0], u1 = up[1];
        bf16x8 bu = cvt8(u0, u1);
        f32x4 d = {0.f, 0.f, 0.f, 0.f};
        d = __builtin_amdgcn_mfma_f32_16x16x32_bf16(ha, bu, d, 0, 0, 0);
        #pragma unroll
        for (int j = 0; j < 4; ++j)
            obase[(size_t)j * OUT_F + o0] = d[j];
    }
}

extern "C" void kernel_launch(void* const* d_in, const int* in_sizes, int n_in,
                              void* d_out, int out_size, void* d_ws, size_t ws_size,
                              hipStream_t stream) {
    const float* X = (const float*)d_in[0];
    const float* U = (const float*)d_in[1];
    const float* S = (const float*)d_in[2];
    const float* V = (const float*)d_in[3];
    float* Out = (float*)d_out;
    float* Hpart = (float*)d_ws;

    // K-split 4 needs 4 * 8192 * 32 * 4 B = 4 MB of workspace
    if (ws_size >= (size_t)4 * 1024 * 1024) {
        lora_h<4><<<dim3(512, 4), 256, 0, stream>>>(X, S, V, Hpart);
        lora_out<<<2048, 256, 0, stream>>>(Hpart, U, Out, 4);
    } else {
        lora_h<1><<<dim3(512, 1), 256, 0, stream>>>(X, S, V, Hpart);
        lora_out<<<2048, 256, 0, stream>>>(Hpart, U, Out, 1);
    }
}

// Round 5
// 90.840 us; speedup vs baseline: 1.0415x; 1.0217x over previous
//
#include <hip/hip_runtime.h>
#include <hip/hip_bf16.h>

typedef __bf16 bf16x8 __attribute__((ext_vector_type(8)));
typedef float  f32x4  __attribute__((ext_vector_type(4)));

#define IN_F   4096
#define OUT_F  4096
#define RANK   32

__device__ __forceinline__ bf16x8 cvt8(float4 a, float4 b) {
    bf16x8 r;
    r[0] = (__bf16)a.x; r[1] = (__bf16)a.y; r[2] = (__bf16)a.z; r[3] = (__bf16)a.w;
    r[4] = (__bf16)b.x; r[5] = (__bf16)b.y; r[6] = (__bf16)b.z; r[7] = (__bf16)b.w;
    return r;
}

// ---------------- Kernel 1: H partials = X @ V^T ----------------
// grid (128, KS), block 256 (4 waves). Block: 64 tokens x F=IN_F/KS features.
// Wave = (rh, fh): rh = rank half (A operand = V rows rh*16..+15),
// fh = feature half (F/2 features, processed in 512-feature chunks).
// Per chunk: V A-frags held in registers (16 steps); per 16-token tile,
// ALL 32 X loads issued independently (xa[16][2]) before any MFMA -> MLP=32.
template <int KS>
__global__ __launch_bounds__(256, 2)
void lora_h(const float* __restrict__ X, const float* __restrict__ S,
            const float* __restrict__ V, float* __restrict__ Hpart)
{
    constexpr int F  = IN_F / KS;        // features per block
    constexpr int NC = (F / 2) / 512;    // 512-feature chunks per wave

    __shared__ float Hp[2][4][16][RANK + 1];   // [fh][tile][token][rank] padded

    const int tid  = threadIdx.x;
    const int wave = tid >> 6;
    const int lane = tid & 63;
    const int rh   = wave & 1;
    const int fh   = wave >> 1;
    const int row  = lane & 15;          // A-row (V rank) / B-col (token)
    const int kg   = lane >> 4;          // k-group

    const int t0 = blockIdx.x * 64;

    f32x4 acc[4] = {};                   // one accumulator per 16-token tile

    for (int c = 0; c < NC; ++c) {
        const int fbase = blockIdx.y * F + fh * (F / 2) + c * 512 + kg * 8;

        // preload V A-fragments for 16 K-steps (held in regs, reused by 4 tiles)
        bf16x8 va[16];
        #pragma unroll
        for (int s = 0; s < 16; ++s) {
            const float4* vp = reinterpret_cast<const float4*>(
                V + (size_t)(rh * 16 + row) * IN_F + fbase + s * 32);
            va[s] = cvt8(vp[0], vp[1]);
        }

        #pragma unroll
        for (int tt = 0; tt < 4; ++tt) {
            const float* xr = X + (size_t)(t0 + tt * 16 + row) * IN_F + fbase;
            // batch-issue all 32 independent X loads for this tile
            float4 xa[16][2];
            #pragma unroll
            for (int s = 0; s < 16; ++s) {
                const float4* xp = reinterpret_cast<const float4*>(xr + s * 32);
                xa[s][0] = xp[0];
                xa[s][1] = xp[1];
            }
            #pragma unroll
            for (int s = 0; s < 16; ++s) {
                bf16x8 xb = cvt8(xa[s][0], xa[s][1]);
                acc[tt] = __builtin_amdgcn_mfma_f32_16x16x32_bf16(va[s], xb, acc[tt], 0, 0, 0);
            }
        }
    }

    // D layout: col(=token)=lane&15, row(=rank)=kg*4+j  (A=V rows -> D row = rank)
    #pragma unroll
    for (int tt = 0; tt < 4; ++tt)
        #pragma unroll
        for (int j = 0; j < 4; ++j)
            Hp[fh][tt][row][rh * 16 + kg * 4 + j] = acc[tt][j];
    __syncthreads();

    // reduce the two feature-half partials, apply S, write block partials
    float* dst = Hpart + ((size_t)blockIdx.y * 512 + blockIdx.x * 4) * 512;
    for (int i = tid; i < 4 * 16 * RANK; i += 256) {
        int tok = i >> 5, r = i & 31;
        float s = Hp[0][tok >> 4][tok & 15][r] + Hp[1][tok >> 4][tok & 15][r];
        dst[i] = s * S[r];               // SCALING == 1.0 folded
    }
}

// ---------------- Kernel 2: Out = H @ U^T ----------------
// grid 2048, block 256 (4 waves). Block b: token-tile tt = b>>2, col-quarter cq = b&3.
// U loads batched 4 tiles deep; stores fire-and-forget.
__global__ __launch_bounds__(256, 4)
void lora_out(const float* __restrict__ Hpart, const float* __restrict__ U,
              float* __restrict__ Out, int nks)
{
    __shared__ float Hs[16][RANK + 1];

    const int tid  = threadIdx.x;
    const int wave = tid >> 6;
    const int lane = tid & 63;
    const int row  = lane & 15;
    const int kg   = lane >> 4;

    const int tt = blockIdx.x >> 2;
    const int cq = blockIdx.x & 3;
    const int t0 = tt * 16;

    // reduce K-split partials for this token tile (512 elements over 256 thr)
    for (int i = tid; i < 16 * RANK; i += 256) {
        float s = 0.f;
        for (int k = 0; k < nks; ++k)
            s += Hpart[((size_t)k * 512 + tt) * 512 + i];
        Hs[i >> 5][i & 31] = s;
    }
    __syncthreads();

    // A fragment: token = row, k(rank) = kg*8+j
    bf16x8 ha;
    #pragma unroll
    for (int j = 0; j < 8; ++j) ha[j] = (__bf16)Hs[row][kg * 8 + j];

    float* obase = Out + (size_t)(t0 + kg * 4) * OUT_F + row;
    const float* ub = U + (size_t)(cq * 1024 + wave * 16 + row) * RANK + kg * 8;

    #pragma unroll
    for (int g = 0; g < 4; ++g) {
        float4 u0[4], u1[4];
        #pragma unroll
        for (int b = 0; b < 4; ++b) {
            const float4* up = reinterpret_cast<const float4*>(
                ub + (size_t)(g * 4 + b) * 64 * RANK);
            u0[b] = up[0];
            u1[b] = up[1];
        }
        #pragma unroll
        for (int b = 0; b < 4; ++b) {
            bf16x8 bu = cvt8(u0[b], u1[b]);
            f32x4 d = {0.f, 0.f, 0.f, 0.f};
            d = __builtin_amdgcn_mfma_f32_16x16x32_bf16(ha, bu, d, 0, 0, 0);
            int o0 = cq * 1024 + ((g * 4 + b) * 4 + wave) * 16;
            #pragma unroll
            for (int j = 0; j < 4; ++j)
                obase[(size_t)j * OUT_F + o0] = d[j];
        }
    }
}

extern "C" void kernel_launch(void* const* d_in, const int* in_sizes, int n_in,
                              void* d_out, int out_size, void* d_ws, size_t ws_size,
                              hipStream_t stream) {
    const float* X = (const float*)d_in[0];
    const float* U = (const float*)d_in[1];
    const float* S = (const float*)d_in[2];
    const float* V = (const float*)d_in[3];
    float* Out = (float*)d_out;
    float* Hpart = (float*)d_ws;

    if (ws_size >= (size_t)4 * 1024 * 1024) {
        // K-split 4: Hpart = 4 * 8192 * 32 * 4 B = 4 MB
        lora_h<4><<<dim3(128, 4), 256, 0, stream>>>(X, S, V, Hpart);
        lora_out<<<2048, 256, 0, stream>>>(Hpart, U, Out, 4);
    } else {
        lora_h<1><<<dim3(128, 1), 256, 0, stream>>>(X, S, V, Hpart);
        lora_out<<<2048, 256, 0, stream>>>(Hpart, U, Out, 1);
    }
}